// Round 3
// baseline (430.373 us; speedup 1.0000x reference)
//
#include <hip/hip_runtime.h>

#define THREADS 256

typedef short bf16x8 __attribute__((ext_vector_type(8)));
typedef float f32x4 __attribute__((ext_vector_type(4)));

__device__ __forceinline__ unsigned short f2bf(float x) {
    unsigned u = __float_as_uint(x);
    return (unsigned short)((u + 0x7FFFu + ((u >> 16) & 1u)) >> 16);
}
__device__ __forceinline__ float bf2f(unsigned short h) {
    return __uint_as_float(((unsigned)h) << 16);
}
__device__ __forceinline__ unsigned score_key(float s) {
    unsigned u = __float_as_uint(s);
    return (u & 0x80000000u) ? ~u : (u | 0x80000000u);
}

// split fp32[8] -> bf16x8 hi + bf16x8 lo (RNE both stages)
__device__ __forceinline__ void split8(const float* __restrict__ f, bf16x8& hv, bf16x8& lv) {
    union { unsigned w[4]; bf16x8 v; } H, L;
#pragma unroll
    for (int q = 0; q < 4; ++q) {
        const float x0 = f[2 * q], x1 = f[2 * q + 1];
        const unsigned b0 = __float_as_uint(x0), b1_ = __float_as_uint(x1);
        const unsigned u0 = b0 + 0x7FFFu + ((b0 >> 16) & 1u);
        const unsigned u1 = b1_ + 0x7FFFu + ((b1_ >> 16) & 1u);
        const float h0 = __uint_as_float(u0 & 0xFFFF0000u);
        const float h1 = __uint_as_float(u1 & 0xFFFF0000u);
        const unsigned l0 = f2bf(x0 - h0), l1 = f2bf(x1 - h1);
        H.w[q] = (u0 >> 16) | ((u1 >> 16) << 16);
        L.w[q] = l0 | (l1 << 16);
    }
    hv = H.v; lv = L.v;
}

__device__ __forceinline__ void async_cp16(const uint4* g, uint4* l) {
    __builtin_amdgcn_global_load_lds(
        (const __attribute__((address_space(1))) unsigned int*)g,
        (__attribute__((address_space(3))) unsigned int*)l, 16, 0, 0);
}

// v[j] = sum_o W2[j,o]*Ws[o];  v[256] = dot(b2,Ws) + bs
__global__ void prep_kernel(const float* __restrict__ W2, const float* __restrict__ b2,
                            const float* __restrict__ Ws, const float* __restrict__ bs,
                            float* __restrict__ v, int OUT) {
    int j = threadIdx.x;
    float acc = 0.f;
    for (int o = 0; o < OUT; ++o) acc += W2[j * OUT + o] * Ws[o];
    v[j] = acc;
    if (j == 0) {
        float c = bs[0];
        for (int o = 0; o < OUT; ++o) c += b2[o] * Ws[o];
        v[256] = c;
    }
}

// W1 [256][256] -> fragment-packed bf16 hi/lo: uint4 index = kt*2048 + (h*16+nt)*64 + lane
// element j of slot = W1[kt*32 + (lane>>4)*8 + j][nt*16 + (lane&15)]
__global__ void prep_w1frag(const float* __restrict__ W1, uint4* __restrict__ wfrag) {
    const int s = blockIdx.x * 256 + threadIdx.x;   // 0..16383
    const int rem = s & 2047;
    const int kt = s >> 11;
    const int c = rem >> 6;
    const int lane = rem & 63;
    const int h = c >> 4;
    const int nt = c & 15;
    const int col = nt * 16 + (lane & 15);
    const int kb = kt * 32 + (lane >> 4) * 8;
    unsigned pk[4];
#pragma unroll
    for (int q = 0; q < 4; ++q) {
        float x0 = W1[(size_t)(kb + 2 * q) * 256 + col];
        float x1 = W1[(size_t)(kb + 2 * q + 1) * 256 + col];
        unsigned short a0, a1;
        if (h == 0) { a0 = f2bf(x0); a1 = f2bf(x1); }
        else {
            a0 = f2bf(x0 - bf2f(f2bf(x0)));
            a1 = f2bf(x1 - bf2f(f2bf(x1)));
        }
        pk[q] = (unsigned)a0 | ((unsigned)a1 << 16);
    }
    wfrag[s] = make_uint4(pk[0], pk[1], pk[2], pk[3]);
}

__global__ void init_bins(unsigned long long* __restrict__ bins, int n) {
    int i = blockIdx.x * blockDim.x + threadIdx.x;
    if (i < n) bins[i] = 0ULL;
}

// Fused: h = desc@W1 + b1 (bf16x4-split MFMA); LN; SiLU; score = h.v + c; gid; bin argmax
// 4 waves/block; wave owns 32 rows x 256 cols. A direct-from-global (wave-private rows),
// B async global->LDS double-buffered, one barrier per K-tile, in-wave epilogue.
__global__ __launch_bounds__(256, 2) void score_kernel(
    const float* __restrict__ desc, const float* __restrict__ kpts,
    const uint4* __restrict__ wfrag,
    const float* __restrict__ b1, const float* __restrict__ g1, const float* __restrict__ be1,
    const int* __restrict__ Hp, const int* __restrict__ Wp,
    const float* __restrict__ v,
    float* __restrict__ scores, unsigned long long* __restrict__ bins,
    int N, int total)
{
    __shared__ uint4 BS[2][32 * 64];   // double-buffered W1 frags (2 x 32KB)
    __shared__ float b1L[256], g1L[256], beL[256], vL[256];

    const int t = threadIdx.x;
    const int lane = t & 63;
    const int w = t >> 6;                    // wave 0..3
    const int l15 = lane & 15, q4 = lane >> 4;
    const int wrow0 = blockIdx.x * 128 + w * 32;

    b1L[t] = b1[t]; g1L[t] = g1[t]; beL[t] = be1[t]; vL[t] = v[t];

    // issue B[kt=0] into BS[0] (wave w handles chunks w*8..w*8+7)
    {
        const uint4* bsrc = wfrag + (w * 8) * 64 + lane;
#pragma unroll
        for (int j = 0; j < 8; ++j)
            async_cp16(bsrc + j * 64, &BS[0][(w * 8 + j) * 64]);
    }

    // A addressing: rowgrp g in {0,1}: row = wrow0 + g*16 + l15, k = kt*32 + q4*8 + j
    const int rA0 = min(wrow0 + l15, total - 1);
    const int rA1 = min(wrow0 + 16 + l15, total - 1);
    const float* pa0 = desc + (size_t)rA0 * 256 + q4 * 8;
    const float* pa1 = desc + (size_t)rA1 * 256 + q4 * 8;
    float4 a00 = *(const float4*)pa0, a01 = *(const float4*)(pa0 + 4);
    float4 a10 = *(const float4*)pa1, a11 = *(const float4*)(pa1 + 4);

    __syncthreads();   // drains vmcnt(0): B[0] in LDS, params visible

    f32x4 acc[2][16];
#pragma unroll
    for (int n = 0; n < 16; ++n) {
        const float bc = b1L[n * 16 + l15];   // fold b1 into accumulator init
        acc[0][n] = (f32x4){bc, bc, bc, bc};
        acc[1][n] = (f32x4){bc, bc, bc, bc};
    }

    for (int kt = 0; kt < 8; ++kt) {
        const int cur = kt & 1;
        // prefetch B[kt+1] (async, drained by end-of-kt barrier)
        if (kt < 7) {
            const uint4* bsrc = wfrag + (size_t)(kt + 1) * 2048 + (w * 8) * 64 + lane;
#pragma unroll
            for (int j = 0; j < 8; ++j)
                async_cp16(bsrc + j * 64, &BS[cur ^ 1][(w * 8 + j) * 64]);
        }
        // convert current A to hi/lo fragments
        bf16x8 ah[2], al[2];
        {
            float f0[8] = {a00.x, a00.y, a00.z, a00.w, a01.x, a01.y, a01.z, a01.w};
            split8(f0, ah[0], al[0]);
            float f1[8] = {a10.x, a10.y, a10.z, a10.w, a11.x, a11.y, a11.z, a11.w};
            split8(f1, ah[1], al[1]);
        }
        // prefetch next A (covered by this kt's compute + barrier drain)
        if (kt < 7) {
            const float* q0 = pa0 + (kt + 1) * 32;
            const float* q1 = pa1 + (kt + 1) * 32;
            a00 = *(const float4*)q0; a01 = *(const float4*)(q0 + 4);
            a10 = *(const float4*)q1; a11 = *(const float4*)(q1 + 4);
        }
        // MFMA: 4 groups of 4 chunks; 4-pass split precision
#pragma unroll
        for (int g = 0; g < 4; ++g) {
            bf16x8 bh[4], bl[4];
#pragma unroll
            for (int j = 0; j < 4; ++j) {
                bh[j] = *(const bf16x8*)&BS[cur][(g * 4 + j) * 64 + lane];
                bl[j] = *(const bf16x8*)&BS[cur][(16 + g * 4 + j) * 64 + lane];
            }
#pragma unroll
            for (int p = 0; p < 4; ++p) {   // hh, hl, lh, ll
#pragma unroll
                for (int j = 0; j < 4; ++j)
#pragma unroll
                    for (int m = 0; m < 2; ++m) {
                        const bf16x8 aa = (p & 2) ? al[m] : ah[m];
                        const bf16x8 bb = (p & 1) ? bl[j] : bh[j];
                        acc[m][g * 4 + j] =
                            __builtin_amdgcn_mfma_f32_16x16x32_bf16(aa, bb, acc[m][g * 4 + j], 0, 0, 0);
                    }
            }
        }
        __syncthreads();   // next B buffer ready; A prefetch complete
    }

    // ---- in-wave epilogue: LN (E[x],E[x^2]) + SiLU + score-dot, 16-lane butterflies
    const float Wf = (float)Wp[0];
    const int Hi = Hp[0];
    const float t02 = (float)(0.2 * (double)Hi);
    const float t05 = (float)(0.5 * (double)Hi);
    const float t03 = (float)(0.3 * (double)Hi);
    const float cterm = v[256];

#pragma unroll
    for (int m = 0; m < 2; ++m)
#pragma unroll
        for (int r = 0; r < 4; ++r) {
            float sx = 0.f, sq = 0.f;
#pragma unroll
            for (int n = 0; n < 16; ++n) {
                const float x = acc[m][n][r];
                sx += x; sq = fmaf(x, x, sq);
            }
#pragma unroll
            for (int mask = 1; mask <= 8; mask <<= 1) {
                sx += __shfl_xor(sx, mask);
                sq += __shfl_xor(sq, mask);
            }
            const float mu = sx * (1.f / 256.f);
            const float var = sq * (1.f / 256.f) - mu * mu;
            const float rs = 1.f / sqrtf(var + 1e-5f);
            float dot = 0.f;
#pragma unroll
            for (int n = 0; n < 16; ++n) {
                const int c = n * 16 + l15;
                const float hv = (acc[m][n][r] - mu) * rs * g1L[c] + beL[c];
                const float sg = 1.f / (1.f + __expf(-hv));
                dot = fmaf(vL[c], hv * sg, dot);
            }
#pragma unroll
            for (int mask = 1; mask <= 8; mask <<= 1) dot += __shfl_xor(dot, mask);

            if (l15 == 0) {
                const int row = wrow0 + m * 16 + q4 * 4 + r;
                if (row < total) {
                    const float sc = dot + cterm;
                    scores[row] = sc;
                    const float x = kpts[(size_t)row * 2 + 0];
                    const float y = kpts[(size_t)row * 2 + 1];
                    int g = -1;
                    if (y > t05) {
                        int bgx = (int)(x / Wf * 16.f); bgx = min(max(bgx, 0), 15);
                        int bgy = (int)((y - t05) / t05 * 6.f); bgy = min(max(bgy, 0), 5);
                        g = 32 + bgy * 16 + bgx;
                    } else if (y > t02) {
                        int mgx = (int)(x / Wf * 8.f); mgx = min(max(mgx, 0), 7);
                        int mgy = (int)((y - t02) / t03 * 4.f); mgy = min(max(mgy, 0), 3);
                        g = mgy * 8 + mgx;
                    }
                    if (g >= 0) {
                        const int bb = row / N;
                        const int n = row - bb * N;
                        const unsigned long long pk =
                            ((unsigned long long)score_key(sc) << 32) | (unsigned)(~(unsigned)n);
                        atomicMax(&bins[bb * 128 + g], pk);
                    }
                }
            }
        }
}

// One block per batch: compact bin winners (bin order), top-k fallback, gather outputs.
__global__ __launch_bounds__(256) void finalize_kernel(
    const float* __restrict__ scores, const unsigned long long* __restrict__ bins,
    const float* __restrict__ desc, const float* __restrict__ kpts,
    const int* __restrict__ tkp, float* __restrict__ out, int B, int N)
{
    const int b = blockIdx.x, t = threadIdx.x;
    const int topk = tkp[0];
    __shared__ int selL[512];
    __shared__ int nselS;
    __shared__ unsigned long long red[256];
    __shared__ unsigned long long binL[128];

    if (t < 128) binL[t] = bins[b * 128 + t];
    __syncthreads();
    if (t == 0) {
        int c = 0;
        for (int i = 0; i < 128; ++i)
            if ((binL[i] >> 32) != 0ULL) selL[c++] = (int)(~(unsigned)binL[i]);
        nselS = c;
    }
    __syncthreads();
    const int nsel = nselS;

    for (int need = nsel; need < topk; ++need) {
        unsigned long long best = 0ULL;
        for (int i = t; i < N; i += THREADS) {
            bool taken = false;
            for (int s2 = 0; s2 < need; ++s2)
                if (selL[s2] == i) { taken = true; break; }
            if (!taken) {
                const unsigned long long pk =
                    ((unsigned long long)score_key(scores[(size_t)b * N + i]) << 32)
                    | (unsigned)(~(unsigned)i);
                if (pk > best) best = pk;
            }
        }
        red[t] = best;
        __syncthreads();
        for (int off = 128; off > 0; off >>= 1) {
            if (t < off) { if (red[t + off] > red[t]) red[t] = red[t + off]; }
            __syncthreads();
        }
        if (t == 0) selL[need] = (int)(~(unsigned)red[0]);
        __syncthreads();
    }

    float* o_feat = out;
    float* o_kpts = out + (size_t)B * topk * 256;
    float* o_idx  = out + (size_t)B * topk * 258;
    for (int e = t; e < topk * 64; e += THREADS) {
        const int j = e >> 6, q4 = e & 63;
        const int n = selL[j];
        *(float4*)&o_feat[((size_t)b * topk + j) * 256 + q4 * 4] =
            *(const float4*)&desc[((size_t)b * N + n) * 256 + q4 * 4];
    }
    for (int j = t; j < topk; j += THREADS) {
        const int n = selL[j];
        o_kpts[((size_t)b * topk + j) * 2 + 0] = kpts[((size_t)b * N + n) * 2 + 0];
        o_kpts[((size_t)b * topk + j) * 2 + 1] = kpts[((size_t)b * N + n) * 2 + 1];
        o_idx[(size_t)b * topk + j] = (float)n;
    }
}

extern "C" void kernel_launch(void* const* d_in, const int* in_sizes, int n_in,
                              void* d_out, int out_size, void* d_ws, size_t ws_size,
                              hipStream_t stream) {
    const float* kpts = (const float*)d_in[0];
    const float* desc = (const float*)d_in[1];
    const int*   Hp   = (const int*)d_in[2];
    const int*   Wp   = (const int*)d_in[3];
    const int*   tkp  = (const int*)d_in[4];
    const float* W1   = (const float*)d_in[5];
    const float* b1   = (const float*)d_in[6];
    const float* g1   = (const float*)d_in[7];
    const float* be1  = (const float*)d_in[8];
    const float* W2   = (const float*)d_in[9];
    const float* b2   = (const float*)d_in[10];
    const float* Ws   = (const float*)d_in[11];
    const float* bs   = (const float*)d_in[12];

    const int total = in_sizes[1] / 256;   // B*N
    const int BT    = out_size / 259;      // B*topk
    const int B     = BT / 128;            // topk = 128 for this problem
    const int N     = total / B;
    const int OUT   = in_sizes[11];        // 128

    float* ws_v      = (float*)d_ws;                       // 257 floats (pad 512)
    float* ws_scores = ws_v + 512;                         // total floats
    size_t off = ((size_t)(512 + total) * 4 + 255) & ~(size_t)255;
    unsigned long long* ws_bins = (unsigned long long*)((char*)d_ws + off);
    size_t off2 = (off + (size_t)B * 128 * 8 + 255) & ~(size_t)255;
    uint4* ws_wfrag = (uint4*)((char*)d_ws + off2);        // 16384 uint4 = 256KB

    prep_kernel<<<1, 256, 0, stream>>>(W2, b2, Ws, bs, ws_v, OUT);
    prep_w1frag<<<64, 256, 0, stream>>>(W1, ws_wfrag);
    init_bins<<<(B * 128 + 255) / 256, 256, 0, stream>>>(ws_bins, B * 128);
    score_kernel<<<(total + 127) / 128, 256, 0, stream>>>(
        desc, kpts, ws_wfrag, b1, g1, be1, Hp, Wp, ws_v, ws_scores, ws_bins, N, total);
    finalize_kernel<<<B, 256, 0, stream>>>(ws_scores, ws_bins, desc, kpts, tkp,
                                           (float*)d_out, B, N);
}